// Round 1
// baseline (838.972 us; speedup 1.0000x reference)
//
#include <hip/hip_runtime.h>

// CircuitModel: sequential Oja/Hebbian plasticity scan.
//   y_t = sigmoid(W_t @ x_t); W_{t+1} = (1 + lr*th1*y^2) W_t + (lr*th0*y) x_t (row-wise)
//   out[t, p] = y_t[observed_idx[p]]
//
// Row-separable: each observed row is an independent length-T recurrence.
// One wave (64 lanes) per observed index; w row lives in registers
// (8 floats/lane). Per step: lane-partial dot -> shfl_xor wave reduce ->
// sigmoid -> rank-1 row update. x_{t+1} is prefetched (recurrence-independent).

constexpr int N_IN  = 512;
constexpr int T     = 2048;
constexpr int N_OBS = 256;

__global__ __launch_bounds__(256) void oja_scan_kernel(
    const float* __restrict__ X,     // [T, N_IN]
    const float* __restrict__ Winit, // [N_OUT, N_IN]
    const float* __restrict__ theta, // [2]
    const int*   __restrict__ obs,   // [N_OBS]
    float*       __restrict__ out)   // [T, N_OBS]
{
    const int wave = (blockIdx.x * blockDim.x + threadIdx.x) >> 6;
    const int lane = threadIdx.x & 63;
    if (wave >= N_OBS) return;

    const int row = obs[wave];

    const float lr  = 1.0f / (float)N_IN;
    const float th0 = theta[0] * lr;   // scale folded in
    const float th1 = theta[1] * lr;

    // This lane owns elements [lane*8, lane*8+8) of the row / of x.
    const float4* Wv = (const float4*)(Winit + (long)row * N_IN);
    float4 w0 = Wv[lane * 2 + 0];
    float4 w1 = Wv[lane * 2 + 1];

    const float4* Xv = (const float4*)X;
    float4 xa = Xv[lane * 2 + 0];
    float4 xb = Xv[lane * 2 + 1];

    for (int t = 0; t < T; ++t) {
        // Prefetch next x chunk (addresses independent of the recurrence;
        // latency hidden behind this step's reduce+sigmoid chain).
        const int tn = (t + 1 < T) ? (t + 1) : (T - 1);
        float4 na = Xv[tn * (N_IN / 4) + lane * 2 + 0];
        float4 nb = Xv[tn * (N_IN / 4) + lane * 2 + 1];

        // Lane-partial dot (two accumulators for a bit of ILP).
        float p0 = w0.x * xa.x + w0.y * xa.y + w0.z * xa.z + w0.w * xa.w;
        float p1 = w1.x * xb.x + w1.y * xb.y + w1.z * xb.z + w1.w * xb.w;
        float p = p0 + p1;

        // Wave-wide reduce (all 64 lanes end with the sum).
        #pragma unroll
        for (int off = 32; off > 0; off >>= 1)
            p += __shfl_xor(p, off, 64);

        const float y = 1.0f / (1.0f + __expf(-p));

        if (lane == 0) out[t * N_OBS + wave] = y;

        // Row update: w = b*w + a*x
        const float a = th0 * y;
        const float b = 1.0f + th1 * y * y;
        w0.x = b * w0.x + a * xa.x;
        w0.y = b * w0.y + a * xa.y;
        w0.z = b * w0.z + a * xa.z;
        w0.w = b * w0.w + a * xa.w;
        w1.x = b * w1.x + a * xb.x;
        w1.y = b * w1.y + a * xb.y;
        w1.z = b * w1.z + a * xb.z;
        w1.w = b * w1.w + a * xb.w;

        xa = na;
        xb = nb;
    }
}

extern "C" void kernel_launch(void* const* d_in, const int* in_sizes, int n_in,
                              void* d_out, int out_size, void* d_ws, size_t ws_size,
                              hipStream_t stream) {
    const float* X     = (const float*)d_in[0];
    const float* Winit = (const float*)d_in[1];
    const float* theta = (const float*)d_in[2];
    const int*   obs   = (const int*)d_in[3];
    float*       out   = (float*)d_out;

    // 256 waves total: 64 blocks x 4 waves (4 waves/CU share L1 for the X stream).
    dim3 grid(64), block(256);
    oja_scan_kernel<<<grid, block, 0, stream>>>(X, Winit, theta, obs, out);
}

// Round 3
// 665.489 us; speedup vs baseline: 1.2607x; 1.2607x over previous
//
#include <hip/hip_runtime.h>

// CircuitModel: sequential Oja/Hebbian plasticity scan.
//   y_t = sigmoid(W_t @ x_t); W_{t+1} = (1 + lr*th1*y^2) W_t + (lr*th0*y) x_t (row-wise)
//   out[t, p] = y_t[observed_idx[p]]
//
// One wave per observed row; w row in registers (8 floats/lane).
// R1 lesson: __shfl_xor = ds_swizzle/bpermute = ~120cy LDS latency/step -> DPP.
// R2 lesson: __builtin_amdgcn_readlane is int(int,int) — passing float
// VALUE-converts (v_cvt_i32_f32, truncation!). Must bitcast both ways.

constexpr int N_IN  = 512;
constexpr int T     = 2048;
constexpr int N_OBS = 256;

// One DPP-add reduce step: v += dpp_move(v). old=0 (additive identity) covers
// masked rows / invalid (shifted-in) source lanes, so no bank-mask trimming
// is needed.
#define DPP_ADD(v, ctrl, rmask)                                                \
    v += __int_as_float(__builtin_amdgcn_update_dpp(                           \
        0, __float_as_int(v), (ctrl), (rmask), 0xf, false))

__device__ __forceinline__ float wave64_sum_bcast(float v) {
    DPP_ADD(v, 0x111, 0xf); // row_shr:1
    DPP_ADD(v, 0x112, 0xf); // row_shr:2
    DPP_ADD(v, 0x114, 0xf); // row_shr:4
    DPP_ADD(v, 0x118, 0xf); // row_shr:8  -> lane 15 of each row16 = row sum
    DPP_ADD(v, 0x142, 0xa); // row_bcast:15 -> lane31 = sum(0..31), lane63 = sum(32..63)
    DPP_ADD(v, 0x143, 0xc); // row_bcast:31 -> lane63 = sum(0..63)
    // Bitcast readlane: builtin is int(int,int); float would value-convert.
    return __int_as_float(__builtin_amdgcn_readlane(__float_as_int(v), 63));
}

__global__ __launch_bounds__(256) void oja_scan_kernel(
    const float* __restrict__ X,     // [T, N_IN]
    const float* __restrict__ Winit, // [N_OUT, N_IN]
    const float* __restrict__ theta, // [2]
    const int*   __restrict__ obs,   // [N_OBS]
    float*       __restrict__ out)   // [T, N_OBS]
{
    const int wave = (blockIdx.x * blockDim.x + threadIdx.x) >> 6;
    const int lane = threadIdx.x & 63;
    if (wave >= N_OBS) return;

    const int row = obs[wave];

    const float lr  = 1.0f / (float)N_IN;
    const float th0 = theta[0] * lr;   // lr folded in
    const float th1 = theta[1] * lr;

    // This lane owns elements [lane*8, lane*8+8) of the row / of x.
    const float4* Wv = (const float4*)(Winit + (long)row * N_IN);
    float4 w0 = Wv[lane * 2 + 0];
    float4 w1 = Wv[lane * 2 + 1];

    const float4* Xv = (const float4*)X;
    float4 xa = Xv[lane * 2 + 0];
    float4 xb = Xv[lane * 2 + 1];

    for (int t = 0; t < T; ++t) {
        // Prefetch next x chunk (recurrence-independent; latency hidden).
        const int tn = (t + 1 < T) ? (t + 1) : (T - 1);
        float4 na = Xv[tn * (N_IN / 4) + lane * 2 + 0];
        float4 nb = Xv[tn * (N_IN / 4) + lane * 2 + 1];

        // Lane-partial dot, 4 accumulators (short dependency chains).
        float p0 = fmaf(w0.x, xa.x, w0.y * xa.y);
        float p1 = fmaf(w0.z, xa.z, w0.w * xa.w);
        float p2 = fmaf(w1.x, xb.x, w1.y * xb.y);
        float p3 = fmaf(w1.z, xb.z, w1.w * xb.w);
        float p  = (p0 + p1) + (p2 + p3);

        // DPP wave reduce (pure VALU; no LDS).
        const float z = wave64_sum_bcast(p);

        const float y = 1.0f / (1.0f + __expf(-z));

        if (lane == 0) out[t * N_OBS + wave] = y;

        // Row update: w = b*w + a*x
        const float a = th0 * y;
        const float b = fmaf(th1 * y, y, 1.0f);
        w0.x = fmaf(b, w0.x, a * xa.x);
        w0.y = fmaf(b, w0.y, a * xa.y);
        w0.z = fmaf(b, w0.z, a * xa.z);
        w0.w = fmaf(b, w0.w, a * xa.w);
        w1.x = fmaf(b, w1.x, a * xb.x);
        w1.y = fmaf(b, w1.y, a * xb.y);
        w1.z = fmaf(b, w1.z, a * xb.z);
        w1.w = fmaf(b, w1.w, a * xb.w);

        xa = na;
        xb = nb;
    }
}

extern "C" void kernel_launch(void* const* d_in, const int* in_sizes, int n_in,
                              void* d_out, int out_size, void* d_ws, size_t ws_size,
                              hipStream_t stream) {
    const float* X     = (const float*)d_in[0];
    const float* Winit = (const float*)d_in[1];
    const float* theta = (const float*)d_in[2];
    const int*   obs   = (const int*)d_in[3];
    float*       out   = (float*)d_out;

    // 256 waves: 64 blocks x 4 waves (one wave per SIMD on 64 CUs).
    dim3 grid(64), block(256);
    oja_scan_kernel<<<grid, block, 0, stream>>>(X, Winit, theta, obs, out);
}

// Round 4
// 392.512 us; speedup vs baseline: 2.1374x; 1.6955x over previous
//
#include <hip/hip_runtime.h>

// CircuitModel: sequential Oja/Hebbian plasticity scan.
//   y_t = sigmoid(w_t.x_t); w_{t+1} = b_t*w_t + a_t*x_t,
//   a_t = lr*th0*y_t, b_t = 1 + lr*th1*y_t^2; out[t,p] = y_t at observed rows.
//
// R1: __shfl_xor = LDS swizzle = ~120cy/step -> DPP reduce.
// R2: readlane must be bitcast (int builtin) or it value-converts.
// R3: still 665us: VMEM latency dominated (prefetch distance 1 < L2/HBM
//     latency; VALUBusy 6% => ~600 stall cy/step). Fix:
//  (a) depth-8 rotating register prefetch pipeline (unroll 8, static slots)
//  (b) linearized scan: z_{t+1} = b_t*Q_t + a_t*G_t with Q_t = w_t.x_{t+1}
//      (dot+reduce starts BEFORE sigmoid resolves) and G_t = x_t.x_{t+1}
//      precomputed into d_ws by gram_kernel. Serial chain ~= sigmoid + 2 fma.

constexpr int N_IN  = 512;
constexpr int T     = 2048;
constexpr int N_OBS = 256;
constexpr int PF    = 8;     // prefetch depth (power of two, divides T)

// DPP add-reduce step; old=0 is the additive identity for invalid lanes.
#define DPP_ADD(v, ctrl, rmask)                                                \
    v += __int_as_float(__builtin_amdgcn_update_dpp(                           \
        0, __float_as_int(v), (ctrl), (rmask), 0xf, false))

__device__ __forceinline__ float wave64_sum_bcast(float v) {
    DPP_ADD(v, 0x111, 0xf); // row_shr:1
    DPP_ADD(v, 0x112, 0xf); // row_shr:2
    DPP_ADD(v, 0x114, 0xf); // row_shr:4
    DPP_ADD(v, 0x118, 0xf); // row_shr:8
    DPP_ADD(v, 0x142, 0xa); // row_bcast:15
    DPP_ADD(v, 0x143, 0xc); // row_bcast:31 -> lane63 = total
    return __int_as_float(__builtin_amdgcn_readlane(__float_as_int(v), 63));
}

__device__ __forceinline__ float dot8(const float4& u0, const float4& u1,
                                      const float4& v0, const float4& v1) {
    float p0 = fmaf(u0.x, v0.x, u0.y * v0.y);
    float p1 = fmaf(u0.z, v0.z, u0.w * v0.w);
    float p2 = fmaf(u1.x, v1.x, u1.y * v1.y);
    float p3 = fmaf(u1.z, v1.z, u1.w * v1.w);
    return (p0 + p1) + (p2 + p3);
}

// ---- Kernel 1: Gram band G[t] = x_t . x_{t+1} (G[T-1] = 0) -----------------
__global__ __launch_bounds__(256) void gram_kernel(const float* __restrict__ X,
                                                   float* __restrict__ G) {
    const int wave = (blockIdx.x * blockDim.x + threadIdx.x) >> 6;
    const int lane = threadIdx.x & 63;
    if (wave >= T) return;
    float p = 0.0f;
    if (wave < T - 1) {
        const float4* xa = (const float4*)(X + (long)wave * N_IN);
        const float4* xb = (const float4*)(X + (long)(wave + 1) * N_IN);
        float4 a0 = xa[lane * 2 + 0], a1 = xa[lane * 2 + 1];
        float4 b0 = xb[lane * 2 + 0], b1 = xb[lane * 2 + 1];
        p = dot8(a0, a1, b0, b1);
    }
    const float s = wave64_sum_bcast(p);
    if (lane == 0) G[wave] = s;
}

// ---- Kernel 2: the scan ----------------------------------------------------
__global__ __launch_bounds__(256) void oja_scan_kernel(
    const float* __restrict__ X,     // [T, N_IN]
    const float* __restrict__ Winit, // [N_OUT, N_IN]
    const float* __restrict__ theta, // [2]
    const int*   __restrict__ obs,   // [N_OBS]
    const float* __restrict__ G,     // [T] gram band (d_ws)
    float*       __restrict__ out)   // [T, N_OBS]
{
    const int wave = (blockIdx.x * blockDim.x + threadIdx.x) >> 6;
    const int lane = threadIdx.x & 63;
    if (wave >= N_OBS) return;

    const int row = obs[wave];
    const float lr  = 1.0f / (float)N_IN;
    const float th0 = theta[0] * lr;
    const float th1 = theta[1] * lr;

    // Row of W in registers: this lane owns elements [lane*8, lane*8+8).
    const float4* Wv = (const float4*)(Winit + (long)row * N_IN);
    float4 w0 = Wv[lane * 2 + 0];
    float4 w1 = Wv[lane * 2 + 1];

    const float4* Xv = (const float4*)X;
    const int lo = lane * 2;

    // Depth-PF rotating prefetch pipeline for x chunks and G entries.
    float4 xb[PF][2];
    float  gb[PF];
    #pragma unroll
    for (int i = 0; i < PF; ++i) {
        xb[i][0] = Xv[i * (N_IN / 4) + lo + 0];
        xb[i][1] = Xv[i * (N_IN / 4) + lo + 1];
        gb[i]    = G[i];
    }

    // z_0 = w_0 . x_0
    float z = wave64_sum_bcast(dot8(w0, w1, xb[0][0], xb[0][1]));

    #pragma unroll 8
    for (int t = 0; t < T; ++t) {
        const int s0 = t & (PF - 1);
        const int s1 = (t + 1) & (PF - 1);

        // Current x_t and x_{t+1} (copies; slot s0 is reloaded below).
        const float4 xa0 = xb[s0][0], xa1 = xb[s0][1];
        const float4 xn0 = xb[s1][0], xn1 = xb[s1][1];
        const float  gt  = gb[s0];

        // Prefetch t+PF into the slot just vacated (clamped at the end;
        // the extra values are never consumed).
        const int tp = (t + PF < T) ? (t + PF) : (T - 1);
        xb[s0][0] = Xv[tp * (N_IN / 4) + lo + 0];
        xb[s0][1] = Xv[tp * (N_IN / 4) + lo + 1];
        gb[s0]    = G[tp];

        // Q_t = w_t . x_{t+1}: independent of this step's sigmoid — the
        // dot + DPP reduce overlap the sigmoid chain.
        const float Q = wave64_sum_bcast(dot8(w0, w1, xn0, xn1));

        // y_t = sigmoid(z_t)
        const float y = __builtin_amdgcn_rcpf(1.0f + __expf(-z));
        if (lane == 0) out[t * N_OBS + wave] = y;

        const float a = th0 * y;
        const float b = fmaf(th1 * y, y, 1.0f);

        // Linearized next pre-activation (algebraically w_{t+1}.x_{t+1}).
        z = fmaf(b, Q, a * gt);

        // w_{t+1} = b*w_t + a*x_t
        w0.x = fmaf(b, w0.x, a * xa0.x);
        w0.y = fmaf(b, w0.y, a * xa0.y);
        w0.z = fmaf(b, w0.z, a * xa0.z);
        w0.w = fmaf(b, w0.w, a * xa0.w);
        w1.x = fmaf(b, w1.x, a * xa1.x);
        w1.y = fmaf(b, w1.y, a * xa1.y);
        w1.z = fmaf(b, w1.z, a * xa1.z);
        w1.w = fmaf(b, w1.w, a * xa1.w);
    }
}

extern "C" void kernel_launch(void* const* d_in, const int* in_sizes, int n_in,
                              void* d_out, int out_size, void* d_ws, size_t ws_size,
                              hipStream_t stream) {
    const float* X     = (const float*)d_in[0];
    const float* Winit = (const float*)d_in[1];
    const float* theta = (const float*)d_in[2];
    const int*   obs   = (const int*)d_in[3];
    float*       out   = (float*)d_out;
    float*       G     = (float*)d_ws;   // T floats = 8 KB

    // Gram band: 2048 waves = 512 blocks x 4 waves.
    gram_kernel<<<512, 256, 0, stream>>>(X, G);

    // Scan: 256 waves = 64 blocks x 4 waves (1 wave/SIMD).
    oja_scan_kernel<<<64, 256, 0, stream>>>(X, Winit, theta, obs, G, out);
}

// Round 5
// 392.510 us; speedup vs baseline: 2.1375x; 1.0000x over previous
//
#include <hip/hip_runtime.h>

// CircuitModel: sequential Oja/Hebbian plasticity scan.
//   y_t = sigmoid(w_t.x_t); w_{t+1} = b_t*w_t + a_t*x_t,
//   a_t = lr*th0*y_t, b_t = 1 + lr*th1*y_t^2; out[t,p] = y_t at observed rows.
//
// R1: __shfl_xor = LDS swizzle ~120cy/step -> DPP reduce.
// R2: readlane is int(int,int) — must bitcast, or it value-converts.
// R3: prefetch distance 1 < VMEM latency -> deep pipeline + 1-step linearization.
// R4: VGPR_Count=56 proved the compiler collapsed the depth-8 pipeline
//     (xb[8][2] alone needs 64 VGPRs); still ~210 stall cy/step. Also learned
//     the floor is per-wave issue: insts/step x 2cy.
// R5: block-linearization, D=8. Per block: 8 dots + 8 interleaved DPP reduces
//     (amortized, latency off critical path for 7/8). Per step: sigmoid +
//     avg ~4.5 Q-update fmas (Gram band, packed 28 floats/block, ONE dword
//     load/block, scalars via compile-time readlane) + 8 w-update fmas.
//     x rows: slot i consumed at step i, reloaded with next block's row i
//     (1..8-step slack, no double buffer, ~64 VGPRs so regalloc can honor it).

constexpr int N_IN    = 512;
constexpr int T       = 2048;
constexpr int N_OBS   = 256;
constexpr int D       = 8;        // linearization block size
constexpr int NBLK    = T / D;    // 256
constexpr int BANDPAD = 64;       // padded packed-band floats per block (28 used)

// Packed band layout for block b (t0=8b): entry k = x_{t0+i} . x_{t0+i+j},
// k = BOFF[i] + (j-1), i=0..6, j=1..7-i  (28 entries).
__device__ constexpr int BOFF[8] = {0, 7, 13, 18, 22, 25, 27, 28};

// DPP add-reduce step; old=0 is the additive identity for invalid lanes.
#define DPP_ADD(v, ctrl, rmask)                                                \
    v += __int_as_float(__builtin_amdgcn_update_dpp(                           \
        0, __float_as_int(v), (ctrl), (rmask), 0xf, false))

__device__ __forceinline__ float wave64_sum_bcast(float v) {
    DPP_ADD(v, 0x111, 0xf); // row_shr:1
    DPP_ADD(v, 0x112, 0xf); // row_shr:2
    DPP_ADD(v, 0x114, 0xf); // row_shr:4
    DPP_ADD(v, 0x118, 0xf); // row_shr:8
    DPP_ADD(v, 0x142, 0xa); // row_bcast:15
    DPP_ADD(v, 0x143, 0xc); // row_bcast:31 -> lane63 = total
    return __int_as_float(__builtin_amdgcn_readlane(__float_as_int(v), 63));
}

__device__ __forceinline__ float dot8(const float4& u0, const float4& u1,
                                      const float4& v0, const float4& v1) {
    float p0 = fmaf(u0.x, v0.x, u0.y * v0.y);
    float p1 = fmaf(u0.z, v0.z, u0.w * v0.w);
    float p2 = fmaf(u1.x, v1.x, u1.y * v1.y);
    float p3 = fmaf(u1.z, v1.z, u1.w * v1.w);
    return (p0 + p1) + (p2 + p3);
}

// ---- Kernel 1: packed Gram band per 8-step block ---------------------------
__global__ __launch_bounds__(256) void gram_kernel(const float* __restrict__ X,
                                                   float* __restrict__ P) {
    const int b    = (blockIdx.x * blockDim.x + threadIdx.x) >> 6;
    const int lane = threadIdx.x & 63;
    if (b >= NBLK) return;
    const int t0 = b * D;
    const float4* Xv = (const float4*)(X + (long)t0 * N_IN);
    float4 r[8][2];
    #pragma unroll
    for (int i = 0; i < 8; ++i) {
        r[i][0] = Xv[i * (N_IN / 4) + lane * 2 + 0];
        r[i][1] = Xv[i * (N_IN / 4) + lane * 2 + 1];
    }
    float s[28];
    #pragma unroll
    for (int i = 0; i < 7; ++i) {
        #pragma unroll
        for (int j = 1; j <= 7 - i; ++j) {
            s[BOFF[i] + j - 1] =
                wave64_sum_bcast(dot8(r[i][0], r[i][1], r[i + j][0], r[i + j][1]));
        }
    }
    if (lane == 0) {
        #pragma unroll
        for (int k = 0; k < 28; ++k) P[b * BANDPAD + k] = s[k];
    }
}

// ---- Kernel 2: the scan ----------------------------------------------------
__global__ __launch_bounds__(256) void oja_scan_kernel(
    const float* __restrict__ X,     // [T, N_IN]
    const float* __restrict__ Winit, // [N_OUT, N_IN]
    const float* __restrict__ theta, // [2]
    const int*   __restrict__ obs,   // [N_OBS]
    const float* __restrict__ P,     // [NBLK, BANDPAD] packed gram band (d_ws)
    float*       __restrict__ out)   // [T, N_OBS]
{
    const int wave = (blockIdx.x * blockDim.x + threadIdx.x) >> 6;
    const int lane = threadIdx.x & 63;
    if (wave >= N_OBS) return;

    const int row = obs[wave];
    const float lr  = 1.0f / (float)N_IN;
    const float th0 = theta[0] * lr;
    const float th1 = theta[1] * lr;

    const float4* Wv = (const float4*)(Winit + (long)row * N_IN);
    float4 w0 = Wv[lane * 2 + 0];
    float4 w1 = Wv[lane * 2 + 1];

    const float4* Xv = (const float4*)X;
    const int lo = lane * 2;

    // x-row slots for the current block: slot i = x_{t0+i}.
    float4 xs[D][2];
    #pragma unroll
    for (int i = 0; i < D; ++i) {
        xs[i][0] = Xv[i * (N_IN / 4) + lo + 0];
        xs[i][1] = Xv[i * (N_IN / 4) + lo + 1];
    }

    // Packed band for block 0 (lane k holds entry k).
    float band  = P[lane];
    float bandn = band;

    float q[D];

    for (int blk = 0; blk < NBLK; ++blk) {
        const int t0 = blk * D;

        // ---- boundary: Q_d = w_{t0} . x_{t0+d}, d=0..7 ----
        float p[D];
        #pragma unroll
        for (int d = 0; d < D; ++d) p[d] = dot8(w0, w1, xs[d][0], xs[d][1]);
        #pragma unroll
        for (int d = 0; d < D; ++d) q[d] = wave64_sum_bcast(p[d]);

        float z = q[0];

        #pragma unroll
        for (int i = 0; i < D; ++i) {
            const float y = __builtin_amdgcn_rcpf(1.0f + __expf(-z));
            if (lane == 0) out[(t0 + i) * N_OBS + wave] = y;

            const float a = th0 * y;
            const float b = fmaf(th1 * y, y, 1.0f);

            // Q updates for future steps of this block (compile-time lanes).
            #pragma unroll
            for (int d = i + 1; d < D; ++d) {
                const int kk = BOFF[i] + (d - i) - 1;
                const float s = __int_as_float(
                    __builtin_amdgcn_readlane(__float_as_int(band), kk));
                q[d] = fmaf(b, q[d], a * s);
            }
            if (i < D - 1) z = q[i + 1];

            // w_{t+1} = b*w + a*x_t
            w0.x = fmaf(b, w0.x, a * xs[i][0].x);
            w0.y = fmaf(b, w0.y, a * xs[i][0].y);
            w0.z = fmaf(b, w0.z, a * xs[i][0].z);
            w0.w = fmaf(b, w0.w, a * xs[i][0].w);
            w1.x = fmaf(b, w1.x, a * xs[i][1].x);
            w1.y = fmaf(b, w1.y, a * xs[i][1].y);
            w1.z = fmaf(b, w1.z, a * xs[i][1].z);
            w1.w = fmaf(b, w1.w, a * xs[i][1].w);

            // Slot i is now dead: prefetch next block's row i (1..8-step slack).
            const int tp = (t0 + D + i < T) ? (t0 + D + i) : (T - 1);
            xs[i][0] = Xv[tp * (N_IN / 4) + lo + 0];
            xs[i][1] = Xv[tp * (N_IN / 4) + lo + 1];

            if (i == 0) {
                const int bn = (blk + 1 < NBLK) ? (blk + 1) : blk;
                bandn = P[bn * BANDPAD + lane];
            }
        }
        band = bandn;
    }
}

extern "C" void kernel_launch(void* const* d_in, const int* in_sizes, int n_in,
                              void* d_out, int out_size, void* d_ws, size_t ws_size,
                              hipStream_t stream) {
    const float* X     = (const float*)d_in[0];
    const float* Winit = (const float*)d_in[1];
    const float* theta = (const float*)d_in[2];
    const int*   obs   = (const int*)d_in[3];
    float*       out   = (float*)d_out;
    float*       P     = (float*)d_ws;   // NBLK*BANDPAD floats = 64 KB

    // Packed gram band: 256 waves = 64 blocks x 4 waves.
    gram_kernel<<<64, 256, 0, stream>>>(X, P);

    // Scan: 256 waves = 64 blocks x 4 waves (1 wave/SIMD).
    oja_scan_kernel<<<64, 256, 0, stream>>>(X, Winit, theta, obs, P, out);
}

// Round 6
// 363.037 us; speedup vs baseline: 2.3110x; 1.0812x over previous
//
#include <hip/hip_runtime.h>

// CircuitModel: sequential Oja/Hebbian plasticity scan.
//   y_t = sigmoid(w_t.x_t); w_{t+1} = b_t*w_t + a_t*x_t,
//   a_t = lr*th0*y_t, b_t = 1 + lr*th1*y_t^2; out[t,p] = y_t at observed rows.
//
// R1: __shfl_xor = LDS swizzle ~120cy/step -> DPP reduce.
// R2: readlane is int(int,int) — must bitcast, or it value-converts.
// R3: prefetch distance 1 < VMEM latency.
// R4: VGPR_Count=56 — regalloc collapsed the depth-8 pipeline.
// R5: block-linearized (D=8) but slot-7's reload still had ~1 step of slack;
//     R4 and R5 tied at 337us scan = 395 cy/step = blended x-load latency
//     (0.75*L2@225 + 0.25*HBM@900). The floor is the MINIMUM issue->use
//     distance across the load rotation, and both designs had ~1 step.
// R6: full ping-pong double buffer: at block b start, issue ALL 17 loads
//     (8 x-rows + band) for block b+1 into the other buffer -> every load
//     gets a full block (>=800cy) of slack. __launch_bounds__(256,1) lifts
//     the VGPR budget (~512/wave) so regalloc can't sink the loads (R4 mode).

constexpr int N_IN    = 512;
constexpr int T       = 2048;
constexpr int N_OBS   = 256;
constexpr int D       = 8;        // linearization block size
constexpr int NBLK    = T / D;    // 256
constexpr int BANDPAD = 64;       // padded packed-band floats per block (28 used)

// Packed band layout for block b (t0=8b): entry k = x_{t0+i} . x_{t0+i+j},
// k = BOFF[i] + (j-1), i=0..6, j=1..7-i  (28 entries).
__device__ constexpr int BOFF[8] = {0, 7, 13, 18, 22, 25, 27, 28};

// DPP add-reduce step; old=0 is the additive identity for invalid lanes.
#define DPP_ADD(v, ctrl, rmask)                                                \
    v += __int_as_float(__builtin_amdgcn_update_dpp(                           \
        0, __float_as_int(v), (ctrl), (rmask), 0xf, false))

__device__ __forceinline__ float wave64_sum_bcast(float v) {
    DPP_ADD(v, 0x111, 0xf); // row_shr:1
    DPP_ADD(v, 0x112, 0xf); // row_shr:2
    DPP_ADD(v, 0x114, 0xf); // row_shr:4
    DPP_ADD(v, 0x118, 0xf); // row_shr:8
    DPP_ADD(v, 0x142, 0xa); // row_bcast:15
    DPP_ADD(v, 0x143, 0xc); // row_bcast:31 -> lane63 = total
    return __int_as_float(__builtin_amdgcn_readlane(__float_as_int(v), 63));
}

__device__ __forceinline__ float dot8(const float4& u0, const float4& u1,
                                      const float4& v0, const float4& v1) {
    float p0 = fmaf(u0.x, v0.x, u0.y * v0.y);
    float p1 = fmaf(u0.z, v0.z, u0.w * v0.w);
    float p2 = fmaf(u1.x, v1.x, u1.y * v1.y);
    float p3 = fmaf(u1.z, v1.z, u1.w * v1.w);
    return (p0 + p1) + (p2 + p3);
}

// ---- Kernel 1: packed Gram band per 8-step block ---------------------------
__global__ __launch_bounds__(256) void gram_kernel(const float* __restrict__ X,
                                                   float* __restrict__ P) {
    const int b    = (blockIdx.x * blockDim.x + threadIdx.x) >> 6;
    const int lane = threadIdx.x & 63;
    if (b >= NBLK) return;
    const int t0 = b * D;
    const float4* Xv = (const float4*)(X + (long)t0 * N_IN);
    float4 r[8][2];
    #pragma unroll
    for (int i = 0; i < 8; ++i) {
        r[i][0] = Xv[i * (N_IN / 4) + lane * 2 + 0];
        r[i][1] = Xv[i * (N_IN / 4) + lane * 2 + 1];
    }
    float s[28];
    #pragma unroll
    for (int i = 0; i < 7; ++i) {
        #pragma unroll
        for (int j = 1; j <= 7 - i; ++j) {
            s[BOFF[i] + j - 1] =
                wave64_sum_bcast(dot8(r[i][0], r[i][1], r[i + j][0], r[i + j][1]));
        }
    }
    if (lane == 0) {
        #pragma unroll
        for (int k = 0; k < 28; ++k) P[b * BANDPAD + k] = s[k];
    }
}

// ---- One scan block: prefetch blk+1 into nxt, process blk from cur ---------
__device__ __forceinline__ void scan_block(
    int blk, int lane, int wave, int lo,
    const float4* __restrict__ Xv, const float* __restrict__ P,
    float* __restrict__ out,
    float4 (&cur)[D][2], float4 (&nxt)[D][2],
    float& band, float4& w0, float4& w1, float th0, float th1)
{
    const int t0 = blk * D;

    // 1) Prefetch block blk+1 (x rows + band) into the other buffer.
    //    cur's consumers never touch nxt -> loads get a full block of slack.
    const int bn = (blk + 1 < NBLK) ? (blk + 1) : blk;
    const int tb = bn * D;
    #pragma unroll
    for (int i = 0; i < D; ++i) {
        nxt[i][0] = Xv[(tb + i) * (N_IN / 4) + lo + 0];
        nxt[i][1] = Xv[(tb + i) * (N_IN / 4) + lo + 1];
    }
    const float bandn = P[bn * BANDPAD + lane];

    // 2) Boundary: Q_d = w_{t0} . x_{t0+d} (8 independent DPP reduce chains).
    float q[D];
    #pragma unroll
    for (int d = 0; d < D; ++d)
        q[d] = wave64_sum_bcast(dot8(w0, w1, cur[d][0], cur[d][1]));

    // 3) Eight steps: sigmoid + Q propagation (Gram scalars via compile-time
    //    readlane from the packed band register) + w rank-1 update.
    float z = q[0];
    #pragma unroll
    for (int i = 0; i < D; ++i) {
        const float y = __builtin_amdgcn_rcpf(1.0f + __expf(-z));
        if (lane == 0) out[(t0 + i) * N_OBS + wave] = y;

        const float a = th0 * y;
        const float b = fmaf(th1 * y, y, 1.0f);

        #pragma unroll
        for (int d = i + 1; d < D; ++d) {
            const int kk = BOFF[i] + (d - i) - 1;
            const float s = __int_as_float(
                __builtin_amdgcn_readlane(__float_as_int(band), kk));
            q[d] = fmaf(b, q[d], a * s);
        }
        if (i < D - 1) z = q[i + 1];

        w0.x = fmaf(b, w0.x, a * cur[i][0].x);
        w0.y = fmaf(b, w0.y, a * cur[i][0].y);
        w0.z = fmaf(b, w0.z, a * cur[i][0].z);
        w0.w = fmaf(b, w0.w, a * cur[i][0].w);
        w1.x = fmaf(b, w1.x, a * cur[i][1].x);
        w1.y = fmaf(b, w1.y, a * cur[i][1].y);
        w1.z = fmaf(b, w1.z, a * cur[i][1].z);
        w1.w = fmaf(b, w1.w, a * cur[i][1].w);
    }
    band = bandn;
}

// ---- Kernel 2: the scan ----------------------------------------------------
__global__ __launch_bounds__(256, 1) void oja_scan_kernel(
    const float* __restrict__ X,     // [T, N_IN]
    const float* __restrict__ Winit, // [N_OUT, N_IN]
    const float* __restrict__ theta, // [2]
    const int*   __restrict__ obs,   // [N_OBS]
    const float* __restrict__ P,     // [NBLK, BANDPAD] packed gram band (d_ws)
    float*       __restrict__ out)   // [T, N_OBS]
{
    const int wave = (blockIdx.x * blockDim.x + threadIdx.x) >> 6;
    const int lane = threadIdx.x & 63;
    if (wave >= N_OBS) return;

    const int row = obs[wave];
    const float lr  = 1.0f / (float)N_IN;
    const float th0 = theta[0] * lr;
    const float th1 = theta[1] * lr;

    const float4* Wv = (const float4*)(Winit + (long)row * N_IN);
    float4 w0 = Wv[lane * 2 + 0];
    float4 w1 = Wv[lane * 2 + 1];

    const float4* Xv = (const float4*)X;
    const int lo = lane * 2;

    // Ping-pong x buffers (2 x 8 rows x 8 floats/lane = 128 VGPRs; budget is
    // ~512/wave at 1 wave/SIMD, so regalloc has no reason to sink the loads).
    float4 bufA[D][2], bufB[D][2];
    #pragma unroll
    for (int i = 0; i < D; ++i) {
        bufA[i][0] = Xv[i * (N_IN / 4) + lo + 0];
        bufA[i][1] = Xv[i * (N_IN / 4) + lo + 1];
    }
    float band = P[lane];

    for (int blk = 0; blk < NBLK; blk += 2) {
        scan_block(blk,     lane, wave, lo, Xv, P, out, bufA, bufB, band,
                   w0, w1, th0, th1);
        scan_block(blk + 1, lane, wave, lo, Xv, P, out, bufB, bufA, band,
                   w0, w1, th0, th1);
    }
}

extern "C" void kernel_launch(void* const* d_in, const int* in_sizes, int n_in,
                              void* d_out, int out_size, void* d_ws, size_t ws_size,
                              hipStream_t stream) {
    const float* X     = (const float*)d_in[0];
    const float* Winit = (const float*)d_in[1];
    const float* theta = (const float*)d_in[2];
    const int*   obs   = (const int*)d_in[3];
    float*       out   = (float*)d_out;
    float*       P     = (float*)d_ws;   // NBLK*BANDPAD floats = 64 KB

    // Packed gram band: 256 waves = 64 blocks x 4 waves.
    gram_kernel<<<64, 256, 0, stream>>>(X, P);

    // Scan: 256 waves = 64 blocks x 4 waves (1 wave/SIMD).
    oja_scan_kernel<<<64, 256, 0, stream>>>(X, Winit, theta, obs, P, out);
}